// Round 3
// baseline (113.136 us; speedup 1.0000x reference)
//
#include <hip/hip_runtime.h>
#include <stdint.h>

// ContrastiveLossInBatch: loss = mean_i [ lse_j(q_i.k_j/T) - q_i.k_i/T ],
// N=8192, C=256, T=0.07. Fused f16-MFMA GEMM + per-lane online logsumexp
// (base-2); cross-lane merge once at kernel end.
//
// R3: LDS-BW-bound fix — 32 rows/wave (2 row-groups), one ds_read_b128 feeds
// two MFMAs (LDS read cycles/CU 98k -> 49k). Double-buffered k-tile staging,
// one barrier per tile. Single finish kernel.
//
// Workspace layout:
//   [0,       4 MiB)  q in f16, pre-scaled by (1/T)*log2(e)
//   [4 MiB,   8 MiB)  k in f16
//   [8 MiB, +256 KiB) per-(split,row) running max M   (SPLIT*N floats)
//   ...               per-(split,row) running sum S
//   ...               per-(split,row) diagonal  P

#define N_ROWS 8192
#define C_DIM  256
#define BM     128                // rows per block; wave owns 32 (2 groups of 16)
#define BN     64
#define SPLIT  8
#define JCOLS  (N_ROWS / SPLIT)   // 1024 columns per split
#define JTILES (JCOLS / BN)       // 16 k-tiles per split
#define TILE_B (BN * C_DIM * 2)   // 32 KiB per k-tile

typedef __attribute__((ext_vector_type(8))) _Float16 half8;
typedef __attribute__((ext_vector_type(4))) _Float16 half4;
typedef __attribute__((ext_vector_type(4))) float    f32x4;

#if __has_builtin(__builtin_amdgcn_exp2f)
#define EXP2(x) __builtin_amdgcn_exp2f(x)
#else
#define EXP2(x) exp2f(x)
#endif
#if __has_builtin(__builtin_amdgcn_logf)
#define LOG2(x) __builtin_amdgcn_logf(x)
#else
#define LOG2(x) log2f(x)
#endif

__device__ __forceinline__ void gload_lds16(const void* g, void* l) {
  __builtin_amdgcn_global_load_lds(
      (const __attribute__((address_space(1))) unsigned int*)g,
      (__attribute__((address_space(3))) unsigned int*)l, 16, 0, 0);
}

// ---- fp32 -> f16 conversion; q gets (1/0.07)*log2(e) folded in -------------
__global__ void cvt_kernel(const float* __restrict__ q, const float* __restrict__ k,
                           _Float16* __restrict__ qh, _Float16* __restrict__ kh) {
  const float QS = 20.60992915555663f;  // (1/0.07) * log2(e)
  int i = blockIdx.x * 256 + threadIdx.x;
  float4 qv = ((const float4*)q)[i];
  float4 kv = ((const float4*)k)[i];
  half4 qo, ko;
  qo[0] = (_Float16)(qv.x * QS); qo[1] = (_Float16)(qv.y * QS);
  qo[2] = (_Float16)(qv.z * QS); qo[3] = (_Float16)(qv.w * QS);
  ko[0] = (_Float16)kv.x; ko[1] = (_Float16)kv.y;
  ko[2] = (_Float16)kv.z; ko[3] = (_Float16)kv.w;
  ((half4*)qh)[i] = qo;
  ((half4*)kh)[i] = ko;
}

// ---- main fused GEMM + per-lane online base-2 logsumexp --------------------
// Block: 256 threads = 4 waves; wave owns 32 rows as 2 groups of 16. A-frags
// (q) live in registers (2 groups x 8 half8 = 64 VGPR). k-tile (64x256 f16 =
// 32 KiB) double-buffered in LDS via global_load_lds, XOR-swizzled 16B chunks
// (0 bank conflicts). One ds_read_b128 feeds TWO MFMAs (both row groups).
// One __syncthreads per tile; staging of tile jt+1 overlaps compute of jt.
__launch_bounds__(256, 2)
__global__ void sim_lse_kernel(const _Float16* __restrict__ qh,
                               const _Float16* __restrict__ kh,
                               float* __restrict__ pM,
                               float* __restrict__ pS,
                               float* __restrict__ pP) {
  __shared__ __align__(16) _Float16 kt[2 * BN * C_DIM];  // 64 KiB (2 buffers)
  const int tid  = threadIdx.x;
  const int lane = tid & 63;
  const int wave = tid >> 6;
  const int l15  = lane & 15;
  const int lg   = lane >> 4;       // quad group 0..3

  const int rb   = blockIdx.x;      // row block 0..63
  const int sp   = blockIdx.y;      // column split 0..7
  const int row0 = rb * BM + wave * 32;   // first of this wave's 32 rows

  // A fragments: group g, lane holds q[row0+g*16+l15][f*32 + lg*8 .. +8)
  half8 afrag[2][8];
#pragma unroll
  for (int g = 0; g < 2; ++g) {
    const _Float16* qr = qh + (size_t)(row0 + g * 16 + l15) * C_DIM + lg * 8;
#pragma unroll
    for (int f = 0; f < 8; ++f)
      afrag[g][f] = *(const half8*)(qr + f * 32);
  }

  // Per-lane state: row = row0 + g*16 + lg*4 + r, cols {cf*16+l15}
  float M[2][4], S[2][4], P[2][4];
#pragma unroll
  for (int g = 0; g < 2; ++g)
#pragma unroll
    for (int r = 0; r < 4; ++r) {
      M[g][r] = -__builtin_inff(); S[g][r] = 0.f; P[g][r] = -__builtin_inff();
    }

  // swizzled LDS base per col-frag: addr = buf*TILE_B + (bbase[cf] ^ (ks*64))
  int bbase[4];
#pragma unroll
  for (int cf = 0; cf < 4; ++cf) {
    int nl = cf * 16 + l15;
    bbase[cf] = nl * 512 + (((nl & 31) * 16) ^ (lg * 16));
  }

  const char* ksrc = (const char*)(kh + (size_t)sp * JCOLS * C_DIM);
  char* lds = (char*)kt;

  // ---- staging helper (inlined twice): 32 KiB, swizzled dest --------------
#define STAGE(BUF, JT)                                                   \
  do {                                                                   \
    const char* src = ksrc + (size_t)(JT) * TILE_B;                      \
    char* dst = lds + (BUF) * TILE_B;                                    \
    _Pragma("unroll")                                                    \
    for (int it = 0; it < 8; ++it) {                                     \
      int linear = it * 4096 + tid * 16;                                 \
      int row = linear >> 9;                                             \
      int c16 = (linear >> 4) & 31;                                      \
      int gc  = c16 ^ (row & 31);                                        \
      gload_lds16(src + row * 512 + gc * 16, dst + linear);              \
    }                                                                    \
  } while (0)

  STAGE(0, 0);

  for (int jt = 0; jt < JTILES; ++jt) {
    const int cur = jt & 1;
    __syncthreads();                 // tile jt staged; buf cur^1 free to fill
    if (jt + 1 < JTILES) STAGE(cur ^ 1, jt + 1);

    // ---- 128x64 per block: 8 K-steps x 4 col-frags x 2 row-groups ---------
    f32x4 acc[2][4];
#pragma unroll
    for (int g = 0; g < 2; ++g)
#pragma unroll
      for (int cf = 0; cf < 4; ++cf) { f32x4 z = {0.f, 0.f, 0.f, 0.f}; acc[g][cf] = z; }

    const char* buf = lds + cur * TILE_B;
#pragma unroll
    for (int ks = 0; ks < 8; ++ks) {
#pragma unroll
      for (int cf = 0; cf < 4; ++cf) {
        half8 b = *(const half8*)(buf + (bbase[cf] ^ (ks * 64)));
        acc[0][cf] = __builtin_amdgcn_mfma_f32_16x16x32_f16(afrag[0][ks], b, acc[0][cf], 0, 0, 0);
        acc[1][cf] = __builtin_amdgcn_mfma_f32_16x16x32_f16(afrag[1][ks], b, acc[1][cf], 0, 0, 0);
      }
    }

    const int j0 = sp * JCOLS + jt * BN;

#pragma unroll
    for (int g = 0; g < 2; ++g) {
      // ---- diagonal capture (wave-uniform; at most 1 tile/split/group) ----
      const int rg0 = row0 + g * 16;
      if (rg0 >= j0 && rg0 < j0 + BN) {
#pragma unroll
        for (int r = 0; r < 4; ++r) {
          int d = rg0 - j0 + lg * 4 + r;   // tile-local column of row's diag
#pragma unroll
          for (int cf = 0; cf < 4; ++cf)
            if (cf * 16 + l15 == d) P[g][r] = acc[g][cf][r];
        }
      }

      // ---- per-lane online logsumexp (base 2), no cross-lane traffic ------
#pragma unroll
      for (int r = 0; r < 4; ++r) {
        float v0 = acc[g][0][r], v1 = acc[g][1][r], v2 = acc[g][2][r], v3 = acc[g][3][r];
        float tmax = fmaxf(fmaxf(v0, v1), fmaxf(v2, v3));
        float newM  = fmaxf(M[g][r], tmax);
        float alpha = EXP2(M[g][r] - newM);   // exp2(-inf)=0 handles init
        float p = EXP2(v0 - newM) + EXP2(v1 - newM) +
                  EXP2(v2 - newM) + EXP2(v3 - newM);
        S[g][r] = fmaf(S[g][r], alpha, p);
        M[g][r] = newM;
      }
    }
  }

  // ---- one-time 16-lane butterfly merge of (M,S), max-merge of P ----------
#pragma unroll
  for (int g = 0; g < 2; ++g)
#pragma unroll
    for (int r = 0; r < 4; ++r) {
#pragma unroll
      for (int off = 1; off < 16; off <<= 1) {
        float Mo = __shfl_xor(M[g][r], off);
        float So = __shfl_xor(S[g][r], off);
        float nm = fmaxf(M[g][r], Mo);
        S[g][r] = S[g][r] * EXP2(M[g][r] - nm) + So * EXP2(Mo - nm);
        M[g][r] = nm;
        P[g][r] = fmaxf(P[g][r], __shfl_xor(P[g][r], off));
      }
    }

  if (l15 == 0) {
#pragma unroll
    for (int g = 0; g < 2; ++g)
#pragma unroll
      for (int r = 0; r < 4; ++r) {
        int grow = row0 + g * 16 + lg * 4 + r;
        pM[(size_t)sp * N_ROWS + grow] = M[g][r];
        pS[(size_t)sp * N_ROWS + grow] = S[g][r];
        pP[(size_t)sp * N_ROWS + grow] = P[g][r];
      }
  }
}

// ---- merge splits per row, convert base-2 -> nats, mean (one block) -------
__global__ void finish_kernel(const float* __restrict__ pM, const float* __restrict__ pS,
                              const float* __restrict__ pP, float* __restrict__ out) {
  const int tid = threadIdx.x;   // 1024 threads, 8 rows each
  float accl = 0.f;
#pragma unroll
  for (int i = 0; i < N_ROWS / 1024; ++i) {
    int r = i * 1024 + tid;
    float m = -__builtin_inff();
#pragma unroll
    for (int s = 0; s < SPLIT; ++s) m = fmaxf(m, pM[s * N_ROWS + r]);
    float ssum = 0.f;
    float pos  = -__builtin_inff();
#pragma unroll
    for (int s = 0; s < SPLIT; ++s) {
      ssum = fmaf(pS[s * N_ROWS + r], EXP2(pM[s * N_ROWS + r] - m), ssum);
      pos = fmaxf(pos, pP[s * N_ROWS + r]);
    }
    accl += (m + LOG2(ssum)) - pos;   // row loss in base-2 units
  }
#pragma unroll
  for (int off = 1; off < 64; off <<= 1) accl += __shfl_xor(accl, off);
  __shared__ float wsum[16];
  if ((tid & 63) == 0) wsum[tid >> 6] = accl;
  __syncthreads();
  if (tid < 64) {
    float v = (tid < 16) ? wsum[tid] : 0.f;
#pragma unroll
    for (int off = 1; off < 16; off <<= 1) v += __shfl_xor(v, off);
    if (tid == 0)
      out[0] = v * (0.69314718055994531f / (float)N_ROWS);  // ln2 * mean
  }
}

extern "C" void kernel_launch(void* const* d_in, const int* in_sizes, int n_in,
                              void* d_out, int out_size, void* d_ws, size_t ws_size,
                              hipStream_t stream) {
  const float* q = (const float*)d_in[0];
  const float* k = (const float*)d_in[1];
  float* out = (float*)d_out;
  char* ws = (char*)d_ws;

  _Float16* qh = (_Float16*)ws;                                  // 4 MiB
  _Float16* kh = (_Float16*)(ws + (size_t)N_ROWS * C_DIM * 2);   // 4 MiB
  float* pM = (float*)(ws + (size_t)N_ROWS * C_DIM * 4);         // 256 KiB each
  float* pS = pM + SPLIT * N_ROWS;
  float* pP = pS + SPLIT * N_ROWS;

  cvt_kernel<<<dim3(N_ROWS * C_DIM / 4 / 256), dim3(256), 0, stream>>>(q, k, qh, kh);
  sim_lse_kernel<<<dim3(N_ROWS / BM, SPLIT), dim3(256), 0, stream>>>(qh, kh, pM, pS, pP);
  finish_kernel<<<dim3(1), dim3(1024), 0, stream>>>(pM, pS, pP, out);
}